// Round 1
// baseline (774.626 us; speedup 1.0000x reference)
//
#include <hip/hip_runtime.h>
#include <math.h>

#define KMAX 8

// ---------------------------------------------------------------------------
// K0: per-expert feature norms in double.  grid = E blocks of 64 threads.
// ---------------------------------------------------------------------------
__global__ void k_efnorm(const float* __restrict__ ef, int D,
                         double* __restrict__ efn) {
    int e = blockIdx.x;
    int lane = threadIdx.x;  // 64
    double s = 0.0;
    for (int i = lane; i < D; i += 64) {
        double v = (double)ef[(size_t)e * D + i];
        s = fma(v, v, s);
    }
    #pragma unroll
    for (int off = 32; off > 0; off >>= 1) s += __shfl_xor(s, off);
    if (lane == 0) efn[e] = sqrt(s);
}

// ---------------------------------------------------------------------------
// K1: scores + top-k selection.  64 tokens/block, 256 threads.
// Assumes E == 32, D % 64 == 0, B % 64 == 0.
// thread (tl, eg): tl = token-in-block (0..63), eg = expert group (0..3);
// each thread owns experts {eg, eg+4, ..., eg+28} for its token, full-D dot
// accumulated in f64 so expert ordering matches the reference essentially
// exactly (mis-selection would blow the absmax threshold).
// ---------------------------------------------------------------------------
__global__ __launch_bounds__(256) void k_scores(
    const float* __restrict__ x, const float* __restrict__ ef,
    const float* __restrict__ trust, const float* __restrict__ stale,
    const double* __restrict__ efn, const int* __restrict__ kp,
    int D, int* __restrict__ idxb)
{
    __shared__ float xs[64][68];      // pad 68: 2-way max on reads (free)
    __shared__ float efs[32][68];
    __shared__ double sc[64][32];
    __shared__ double xxs[64];

    int tid = threadIdx.x;
    int tl = tid >> 2, eg = tid & 3;
    int tb = blockIdx.x * 64;

    double acc[8] = {0, 0, 0, 0, 0, 0, 0, 0};
    double accxx = 0.0;
    int nch = D / 64;

    for (int ch = 0; ch < nch; ++ch) {
        // x chunk: 64x64 f32 = 1024 float4, 4 per thread, coalesced
        #pragma unroll
        for (int t = 0; t < 4; ++t) {
            int id = t * 256 + tid;
            int r = id >> 4, c4 = id & 15;
            float4 v = *reinterpret_cast<const float4*>(
                &x[(size_t)(tb + r) * D + ch * 64 + c4 * 4]);
            *reinterpret_cast<float4*>(&xs[r][c4 * 4]) = v;
        }
        // ef chunk: 32x64 = 512 float4, 2 per thread
        #pragma unroll
        for (int t = 0; t < 2; ++t) {
            int id = t * 256 + tid;
            int r = id >> 4, c4 = id & 15;
            float4 v = *reinterpret_cast<const float4*>(
                &ef[(size_t)r * D + ch * 64 + c4 * 4]);
            *reinterpret_cast<float4*>(&efs[r][c4 * 4]) = v;
        }
        __syncthreads();
        #pragma unroll 8
        for (int d = 0; d < 64; ++d) {
            double xd = (double)xs[tl][d];
            accxx = fma(xd, xd, accxx);
            #pragma unroll
            for (int j = 0; j < 8; ++j)
                acc[j] = fma(xd, (double)efs[eg + 4 * j][d], acc[j]);
        }
        __syncthreads();
    }

    if (eg == 0) xxs[tl] = accxx;
    __syncthreads();

    double xn = fmax(sqrt(xxs[tl]), 1e-8);
    #pragma unroll
    for (int j = 0; j < 8; ++j) {
        int e = eg + 4 * j;
        double en = fmax(efn[e], 1e-8);
        double cosv = acc[j] / (xn * en);
        double sim = (cosv + 1.0) * 0.5;
        double st = fmax(0.0, 1.0 - (double)stale[e]);
        sc[tl][e] = 0.4 * (double)trust[e] + 0.4 * sim + 0.2 * st;
    }
    __syncthreads();

    // top-k: strict > scan in increasing e == tie-break to lowest index,
    // matching jax.lax.top_k's selected SET.
    if (tid < 64) {
        int kk = kp[0]; if (kk < 1) kk = 1; if (kk > KMAX) kk = KMAX;
        unsigned mask = 0;
        int t = tb + tid;
        for (int p = 0; p < kk; ++p) {
            double bv = -1e300; int be = 0;
            for (int e = 0; e < 32; ++e) {
                double v = sc[tid][e];
                if (!((mask >> e) & 1u) && v > bv) { bv = v; be = e; }
            }
            mask |= 1u << be;
            idxb[(size_t)t * KMAX + p] = be;
        }
    }
}

// ---------------------------------------------------------------------------
// K2: scatter tokens into per-expert lists (counts pre-zeroed).
// ---------------------------------------------------------------------------
__global__ void k_build(const int* __restrict__ idxb, const int* __restrict__ kp,
                        int B, int* __restrict__ counts, int* __restrict__ lists) {
    int t = blockIdx.x * blockDim.x + threadIdx.x;
    if (t >= B) return;
    int kk = kp[0]; if (kk < 1) kk = 1; if (kk > KMAX) kk = KMAX;
    for (int p = 0; p < kk; ++p) {
        int e = idxb[(size_t)t * KMAX + p];
        int pos = atomicAdd(&counts[e], 1);
        lists[(size_t)e * B + pos] = t;
    }
}

// ---------------------------------------------------------------------------
// K3: grouped expert GEMM.  grid = (ceil(B/64), C/64, E), 256 threads.
// Block: 64 gathered tokens x 64 output cols for expert bz, K-loop over D in
// chunks of 64 staged in LDS.  Each thread: 4x4 outputs (rows ty+16i, cols
// tx+16j), float4 LDS reads.  Epilogue: out[t][c] += (acc + bias)/k  (atomic;
// a token appears in k different expert groups).  d_out pre-zeroed.
// ---------------------------------------------------------------------------
__global__ __launch_bounds__(256) void k_moe(
    const float* __restrict__ x, const float* __restrict__ W,
    const float* __restrict__ bias, const int* __restrict__ lists,
    const int* __restrict__ counts, const int* __restrict__ kp,
    int B, int C, int D, float* __restrict__ out)
{
    int e = blockIdx.z;
    int cnt = counts[e];
    int row0 = blockIdx.x * 64;
    if (row0 >= cnt) return;           // uniform: safe before barriers
    int col0 = blockIdx.y * 64;
    int nt = min(64, cnt - row0);

    __shared__ float xs[64][68];
    __shared__ float wsh[64][68];
    __shared__ int toks[64];

    int tid = threadIdx.x;
    if (tid < 64) toks[tid] = (tid < nt) ? lists[(size_t)e * B + row0 + tid] : 0;
    __syncthreads();

    int tx = tid & 15, ty = tid >> 4;
    float acc[4][4];
    #pragma unroll
    for (int i = 0; i < 4; ++i)
        #pragma unroll
        for (int j = 0; j < 4; ++j) acc[i][j] = 0.f;

    int nch = D / 64;
    for (int ch = 0; ch < nch; ++ch) {
        #pragma unroll
        for (int t = 0; t < 4; ++t) {
            int id = t * 256 + tid;
            int r = id >> 4, c4 = id & 15;
            float4 v;
            if (r < nt)
                v = *reinterpret_cast<const float4*>(
                    &x[(size_t)toks[r] * D + ch * 64 + c4 * 4]);
            else
                v = make_float4(0.f, 0.f, 0.f, 0.f);
            *reinterpret_cast<float4*>(&xs[r][c4 * 4]) = v;

            float4 wv = *reinterpret_cast<const float4*>(
                &W[((size_t)e * C + col0 + r) * D + ch * 64 + c4 * 4]);
            *reinterpret_cast<float4*>(&wsh[r][c4 * 4]) = wv;
        }
        __syncthreads();
        #pragma unroll
        for (int d = 0; d < 64; d += 4) {
            float4 A[4], Bv[4];
            #pragma unroll
            for (int i = 0; i < 4; ++i)
                A[i] = *reinterpret_cast<const float4*>(&xs[ty + 16 * i][d]);
            #pragma unroll
            for (int j = 0; j < 4; ++j)
                Bv[j] = *reinterpret_cast<const float4*>(&wsh[tx + 16 * j][d]);
            #pragma unroll
            for (int i = 0; i < 4; ++i)
                #pragma unroll
                for (int j = 0; j < 4; ++j) {
                    acc[i][j] += A[i].x * Bv[j].x;
                    acc[i][j] += A[i].y * Bv[j].y;
                    acc[i][j] += A[i].z * Bv[j].z;
                    acc[i][j] += A[i].w * Bv[j].w;
                }
        }
        __syncthreads();
    }

    int kk = kp[0]; if (kk < 1) kk = 1; if (kk > KMAX) kk = KMAX;
    float invk = 1.0f / (float)kk;
    #pragma unroll
    for (int j = 0; j < 4; ++j) {
        int c = col0 + tx + 16 * j;
        float bv = bias[(size_t)e * C + c];
        #pragma unroll
        for (int i = 0; i < 4; ++i) {
            int r = ty + 16 * i;
            if (r < nt)
                atomicAdd(&out[(size_t)toks[r] * C + c], invk * (acc[i][j] + bv));
        }
    }
}

// ---------------------------------------------------------------------------
extern "C" void kernel_launch(void* const* d_in, const int* in_sizes, int n_in,
                              void* d_out, int out_size, void* d_ws, size_t ws_size,
                              hipStream_t stream) {
    const float* x     = (const float*)d_in[0];
    const float* ef    = (const float*)d_in[1];
    const float* trust = (const float*)d_in[2];
    const float* stale = (const float*)d_in[3];
    const float* W     = (const float*)d_in[4];
    const float* b     = (const float*)d_in[5];
    const int*   kp    = (const int*)d_in[6];

    int E = in_sizes[2];            // 32
    int D = in_sizes[1] / E;        // 1024
    int B = in_sizes[0] / D;        // 8192
    int C = in_sizes[5] / E;        // 256
    float* out = (float*)d_out;

    // workspace layout
    char* ws = (char*)d_ws;
    double* efn  = (double*)ws;                                   // E doubles
    int* idxb    = (int*)(ws + 256);                              // B*KMAX ints
    size_t off_counts = 256 + (size_t)B * KMAX * 4;
    int* counts  = (int*)(ws + off_counts);                       // E ints (padded to 256B)
    int* lists   = (int*)(ws + off_counts + 256);                 // E*B ints

    hipMemsetAsync(counts, 0, 256, stream);
    hipMemsetAsync(d_out, 0, (size_t)out_size * sizeof(float), stream);

    k_efnorm<<<E, 64, 0, stream>>>(ef, D, efn);
    k_scores<<<B / 64, 256, 0, stream>>>(x, ef, trust, stale, efn, kp, D, idxb);
    k_build<<<(B + 255) / 256, 256, 0, stream>>>(idxb, kp, B, counts, lists);

    dim3 grid((B + 63) / 64, C / 64, E);
    k_moe<<<grid, 256, 0, stream>>>(x, W, b, lists, counts, kp, B, C, D, out);
}

// Round 2
// 512.964 us; speedup vs baseline: 1.5101x; 1.5101x over previous
//
#include <hip/hip_runtime.h>
#include <math.h>

#define KMAX 8

typedef short s16x8 __attribute__((ext_vector_type(8)));
typedef float f32x4 __attribute__((ext_vector_type(4)));

__device__ inline ushort f2bf(float f) {
    union { float f; unsigned u; } v; v.f = f;
    unsigned r = v.u + 0x7fffu + ((v.u >> 16) & 1u);   // RNE
    return (ushort)(r >> 16);
}

// ---------------------------------------------------------------------------
// K0: per-expert feature norms in double.  grid = E blocks of 64 threads.
// ---------------------------------------------------------------------------
__global__ void k_efnorm(const float* __restrict__ ef, int D,
                         double* __restrict__ efn) {
    int e = blockIdx.x;
    int lane = threadIdx.x;  // 64
    double s = 0.0;
    for (int i = lane; i < D; i += 64) {
        double v = (double)ef[(size_t)e * D + i];
        s = fma(v, v, s);
    }
    #pragma unroll
    for (int off = 32; off > 0; off >>= 1) s += __shfl_xor(s, off);
    if (lane == 0) efn[e] = sqrt(s);
}

// ---------------------------------------------------------------------------
// K1: scores + top-k + scatter (fused).  32 tokens/block, 256 threads,
// B/32 = 256 blocks.  Assumes E == 32, D % 64 == 0, B % 32 == 0.
// thread (tl, eg): tl = token (0..31), eg = expert group (0..7); each thread
// owns experts {eg, eg+8, eg+16, eg+24}.  Dots accumulated in f64 (float4 LDS
// reads) so top-k ordering matches the reference exactly — a mis-selected
// borderline token costs ~0.28 absmax vs the 3.16e-2 threshold.
// ---------------------------------------------------------------------------
__global__ __launch_bounds__(256) void k_scores(
    const float* __restrict__ x, const float* __restrict__ ef,
    const float* __restrict__ trust, const float* __restrict__ stale,
    const double* __restrict__ efn, const int* __restrict__ kp,
    int D, int B, int* __restrict__ counts, int* __restrict__ lists)
{
    __shared__ float xs[32][72];     // pitch 72 f32 = 288B (16B-aligned rows)
    __shared__ float efs[32][72];
    __shared__ double sc[32][32];

    int tid = threadIdx.x;
    int tl = tid >> 3, eg = tid & 7;
    int tb = blockIdx.x * 32;

    double acc[4] = {0, 0, 0, 0};
    double axx = 0.0;
    int nch = D / 64;

    for (int ch = 0; ch < nch; ++ch) {
        #pragma unroll
        for (int t = 0; t < 2; ++t) {           // 512 float4 each for x, ef
            int id = t * 256 + tid;
            int r = id >> 4, q = id & 15;
            float4 v = *(const float4*)&x[(size_t)(tb + r) * D + ch * 64 + q * 4];
            *(float4*)&xs[r][q * 4] = v;
            float4 w = *(const float4*)&ef[(size_t)r * D + ch * 64 + q * 4];
            *(float4*)&efs[r][q * 4] = w;
        }
        __syncthreads();
        #pragma unroll 4
        for (int q = 0; q < 16; ++q) {
            float4 xv = *(const float4*)&xs[tl][q * 4];
            double x0 = xv.x, x1 = xv.y, x2 = xv.z, x3 = xv.w;
            axx = fma(x0, x0, fma(x1, x1, fma(x2, x2, fma(x3, x3, axx))));
            #pragma unroll
            for (int j = 0; j < 4; ++j) {
                float4 ev = *(const float4*)&efs[eg + 8 * j][q * 4];
                acc[j] = fma(x0, (double)ev.x, acc[j]);
                acc[j] = fma(x1, (double)ev.y, acc[j]);
                acc[j] = fma(x2, (double)ev.z, acc[j]);
                acc[j] = fma(x3, (double)ev.w, acc[j]);
            }
        }
        __syncthreads();
    }

    double xn = fmax(sqrt(axx), 1e-8);
    #pragma unroll
    for (int j = 0; j < 4; ++j) {
        int e = eg + 8 * j;
        double en = fmax(efn[e], 1e-8);
        double cosv = acc[j] / (xn * en);
        sc[tl][e] = 0.4 * (double)trust[e] + 0.2 * (cosv + 1.0)
                  + 0.2 * fmax(0.0, 1.0 - (double)stale[e]);
    }
    __syncthreads();

    // top-k (strict > scan, increasing e == lowest-index tie-break, matching
    // jax.lax.top_k's selected set) + scatter into per-expert lists.
    if (tid < 32) {
        int kk = kp[0]; kk = kk < 1 ? 1 : (kk > KMAX ? KMAX : kk);
        unsigned mask = 0;
        int t = tb + tid;
        for (int p = 0; p < kk; ++p) {
            double bv = -1e300; int be = 0;
            #pragma unroll
            for (int e = 0; e < 32; ++e) {
                double v = sc[tid][e];
                if (!((mask >> e) & 1u) && v > bv) { bv = v; be = e; }
            }
            mask |= 1u << be;
            int pos = atomicAdd(&counts[be], 1);
            lists[(size_t)be * B + pos] = t;
        }
    }
}

// ---------------------------------------------------------------------------
// K2: grouped expert GEMM on MFMA bf16.
// grid = (ceil(B/128), ceil(C/256), E), 512 threads = 8 waves (2 row x 4 col),
// tile 128 tokens x 256 cols, BK=64.  f32 global reads converted to bf16 on
// the fly into padded LDS (pitch 72 bf16 = 144B = 9x16B: b128-aligned, ~2-way
// bank aliasing = free).  Each wave: 64x64 via acc[4][4] of 16x16x32 MFMA.
// Epilogue: out[t][c] += (acc + bias)/k  (atomic; k writers per element).
// ---------------------------------------------------------------------------
__global__ __launch_bounds__(512) void k_moe(
    const float* __restrict__ x, const float* __restrict__ W,
    const float* __restrict__ bias, const int* __restrict__ lists,
    const int* __restrict__ counts, const int* __restrict__ kp,
    int B, int C, int D, float* __restrict__ out)
{
    int e = blockIdx.z;
    int cnt = counts[e];
    int row0 = blockIdx.x * 128;
    if (row0 >= cnt) return;            // uniform: safe before barriers
    int col0 = blockIdx.y * 256;
    int nt = min(128, cnt - row0);

    __shared__ ushort xs[128 * 72];
    __shared__ ushort wsh[256 * 72];
    __shared__ int toks[128];

    int tid = threadIdx.x;
    if (tid < 128) toks[tid] = (tid < nt) ? lists[(size_t)e * B + row0 + tid] : 0;
    __syncthreads();

    int lane = tid & 63, wid = tid >> 6;
    int wr = wid >> 2, wc = wid & 3;    // wave tile: rows wr*64, cols wc*64
    int l15 = lane & 15, l16 = lane >> 4;

    f32x4 acc[4][4];
    #pragma unroll
    for (int m = 0; m < 4; ++m)
        #pragma unroll
        for (int n = 0; n < 4; ++n) acc[m][n] = (f32x4){0.f, 0.f, 0.f, 0.f};

    int nch = D / 64;
    for (int ch = 0; ch < nch; ++ch) {
        int k0 = ch * 64;
        // stage x-tile: 128 rows x 16 float4 -> bf16, 4 ids/thread
        #pragma unroll
        for (int t = 0; t < 4; ++t) {
            int id = t * 512 + tid;
            int r = id >> 4, q = id & 15;
            float4 v = (r < nt)
                ? *(const float4*)&x[(size_t)toks[r] * D + k0 + q * 4]
                : make_float4(0.f, 0.f, 0.f, 0.f);
            ushort4 u;
            u.x = f2bf(v.x); u.y = f2bf(v.y); u.z = f2bf(v.z); u.w = f2bf(v.w);
            *(ushort4*)&xs[r * 72 + q * 4] = u;
        }
        // stage W-tile: 256 rows x 16 float4 -> bf16, 8 ids/thread
        #pragma unroll
        for (int t = 0; t < 8; ++t) {
            int id = t * 512 + tid;
            int r = id >> 4, q = id & 15;
            float4 v = *(const float4*)&W[((size_t)e * C + col0 + r) * D + k0 + q * 4];
            ushort4 u;
            u.x = f2bf(v.x); u.y = f2bf(v.y); u.z = f2bf(v.z); u.w = f2bf(v.w);
            *(ushort4*)&wsh[r * 72 + q * 4] = u;
        }
        __syncthreads();
        #pragma unroll
        for (int ks = 0; ks < 2; ++ks) {
            s16x8 a[4], bf[4];
            #pragma unroll
            for (int m = 0; m < 4; ++m)
                a[m] = *(const s16x8*)&xs[(wr * 64 + m * 16 + l15) * 72 + ks * 32 + l16 * 8];
            #pragma unroll
            for (int n = 0; n < 4; ++n)
                bf[n] = *(const s16x8*)&wsh[(wc * 64 + n * 16 + l15) * 72 + ks * 32 + l16 * 8];
            #pragma unroll
            for (int m = 0; m < 4; ++m)
                #pragma unroll
                for (int n = 0; n < 4; ++n)
                    acc[m][n] = __builtin_amdgcn_mfma_f32_16x16x32_bf16(
                        a[m], bf[n], acc[m][n], 0, 0, 0);
        }
        __syncthreads();
    }

    int kk = kp[0]; kk = kk < 1 ? 1 : (kk > KMAX ? KMAX : kk);
    float invk = 1.0f / (float)kk;
    // C/D layout (m89-verified): col = lane&15, row = (lane>>4)*4 + reg
    #pragma unroll
    for (int m = 0; m < 4; ++m) {
        int rbase = wr * 64 + m * 16 + l16 * 4;
        #pragma unroll
        for (int n = 0; n < 4; ++n) {
            int col = col0 + wc * 64 + n * 16 + l15;
            float bv = bias[(size_t)e * C + col];
            #pragma unroll
            for (int r = 0; r < 4; ++r) {
                int rl = rbase + r;
                if (rl < nt)
                    atomicAdd(&out[(size_t)toks[rl] * C + col],
                              invk * (acc[m][n][r] + bv));
            }
        }
    }
}

// ---------------------------------------------------------------------------
extern "C" void kernel_launch(void* const* d_in, const int* in_sizes, int n_in,
                              void* d_out, int out_size, void* d_ws, size_t ws_size,
                              hipStream_t stream) {
    const float* x     = (const float*)d_in[0];
    const float* ef    = (const float*)d_in[1];
    const float* trust = (const float*)d_in[2];
    const float* stale = (const float*)d_in[3];
    const float* W     = (const float*)d_in[4];
    const float* b     = (const float*)d_in[5];
    const int*   kp    = (const int*)d_in[6];

    int E = in_sizes[2];            // 32
    int D = in_sizes[1] / E;        // 1024
    int B = in_sizes[0] / D;        // 8192
    int C = in_sizes[5] / E;        // 256
    float* out = (float*)d_out;

    // workspace: efn (256B) | counts (256B) | lists (E*B*4)  ~= 1.05 MB
    char* ws = (char*)d_ws;
    double* efn = (double*)ws;
    int* counts = (int*)(ws + 256);
    int* lists  = (int*)(ws + 512);

    hipMemsetAsync(counts, 0, 256, stream);
    hipMemsetAsync(d_out, 0, (size_t)out_size * sizeof(float), stream);

    k_efnorm<<<E, 64, 0, stream>>>(ef, D, efn);
    k_scores<<<B / 32, 256, 0, stream>>>(x, ef, trust, stale, efn, kp, D, B,
                                         counts, lists);
    dim3 grid((B + 127) / 128, (C + 255) / 256, E);
    k_moe<<<grid, 512, 0, stream>>>(x, W, b, lists, counts, kp, B, C, D, out);
}

// Round 3
// 428.920 us; speedup vs baseline: 1.8060x; 1.1959x over previous
//
#include <hip/hip_runtime.h>
#include <math.h>

#define KMAX 8

typedef short s16x8 __attribute__((ext_vector_type(8)));
typedef float f32x4 __attribute__((ext_vector_type(4)));

__device__ inline ushort f2bf(float f) {
    union { float f; unsigned u; } v; v.f = f;
    unsigned r = v.u + 0x7fffu + ((v.u >> 16) & 1u);   // RNE
    return (ushort)(r >> 16);
}

__device__ inline void gload_lds16(const void* g, void* l) {
    __builtin_amdgcn_global_load_lds(
        (const __attribute__((address_space(1))) unsigned int*)g,
        (__attribute__((address_space(3))) unsigned int*)l, 16, 0, 0);
}

// ---------------------------------------------------------------------------
// K0: per-expert feature norms in double.  grid = E blocks of 64 threads.
// ---------------------------------------------------------------------------
__global__ void k_efnorm(const float* __restrict__ ef, int D,
                         double* __restrict__ efn) {
    int e = blockIdx.x;
    int lane = threadIdx.x;  // 64
    double s = 0.0;
    for (int i = lane; i < D; i += 64) {
        double v = (double)ef[(size_t)e * D + i];
        s = fma(v, v, s);
    }
    #pragma unroll
    for (int off = 32; off > 0; off >>= 1) s += __shfl_xor(s, off);
    if (lane == 0) efn[e] = sqrt(s);
}

// ---------------------------------------------------------------------------
// K1: x -> bf16 copy + per-token L2 norm (f64).  4 tokens/block (4 waves),
// wave per token.  Assumes D == 1024 multiples handled by q-loop D/256.
// ---------------------------------------------------------------------------
__global__ __launch_bounds__(256) void k_prep_x(
    const float* __restrict__ x, int D, ushort* __restrict__ xbf,
    double* __restrict__ xnorm) {
    int t = blockIdx.x * 4 + (threadIdx.x >> 6);
    int lane = threadIdx.x & 63;
    double s = 0.0;
    int nq = D / 256;
    for (int q = 0; q < nq; ++q) {
        float4 v = *(const float4*)&x[(size_t)t * D + q * 256 + lane * 4];
        ushort4 u;
        u.x = f2bf(v.x); u.y = f2bf(v.y); u.z = f2bf(v.z); u.w = f2bf(v.w);
        *(ushort4*)&xbf[(size_t)t * D + q * 256 + lane * 4] = u;
        double a = v.x, b = v.y, c = v.z, d = v.w;
        s = fma(a, a, fma(b, b, fma(c, c, fma(d, d, s))));
    }
    #pragma unroll
    for (int off = 32; off > 0; off >>= 1) s += __shfl_xor(s, off);
    if (lane == 0) xnorm[t] = sqrt(s);
}

// ---------------------------------------------------------------------------
// K2: W -> bf16.  grid covers n/4 elements exactly (n % 1024 == 0).
// ---------------------------------------------------------------------------
__global__ __launch_bounds__(256) void k_prep_w(
    const float* __restrict__ W, ushort* __restrict__ wbf) {
    size_t id = (size_t)blockIdx.x * 256 + threadIdx.x;
    float4 v = *(const float4*)&W[id * 4];
    ushort4 u;
    u.x = f2bf(v.x); u.y = f2bf(v.y); u.z = f2bf(v.z); u.w = f2bf(v.w);
    *(ushort4*)&wbf[id * 4] = u;
}

// ---------------------------------------------------------------------------
// K3: scores + top-k + scatter.  32 tokens/block, 256 threads, B/32 blocks.
// thread (tp = tid>>4, eg = tid&15): tokens {2tp, 2tp+1} x experts {eg, eg+16}.
// Dots: f32 FMA chains per 64-elem chunk, f64 accumulation across chunks
// (score perturbation ~1e-9 << the reference's own f32 rounding ~6e-8, which
// rounds 1-2 proved the dataset's top-k gaps tolerate).
// LDS: exact-pitch-64 rows with seg-XOR swizzle (seg' = q ^ (row&15)) ->
// conflict-free broadcast-heavy b128 reads.  Assumes E==32, D%64==0, B%32==0.
// ---------------------------------------------------------------------------
__global__ __launch_bounds__(256) void k_scores2(
    const float* __restrict__ x, const float* __restrict__ ef,
    const float* __restrict__ trust, const float* __restrict__ stale,
    const double* __restrict__ efn, const double* __restrict__ xnorm,
    const int* __restrict__ kp, int D, int B,
    int* __restrict__ counts, int* __restrict__ lists)
{
    __shared__ float xs[32 * 64];
    __shared__ float efs[32 * 64];
    __shared__ double sc[32 * 32];

    int tid = threadIdx.x;
    int tp = tid >> 4, eg = tid & 15;
    int tb = blockIdx.x * 32;
    int r0 = 2 * tp, r1 = 2 * tp + 1;
    int r0s = r0 & 15, r1s = r1 & 15;

    double accd[4] = {0, 0, 0, 0};
    int nch = D / 64;

    for (int ch = 0; ch < nch; ++ch) {
        #pragma unroll
        for (int t = 0; t < 2; ++t) {
            int id = t * 256 + tid;
            int r = id >> 4, q = id & 15;
            int sw = (q ^ (r & 15)) << 2;
            float4 v = *(const float4*)&x[(size_t)(tb + r) * D + ch * 64 + q * 4];
            *(float4*)&xs[r * 64 + sw] = v;
            float4 w = *(const float4*)&ef[(size_t)r * D + ch * 64 + q * 4];
            *(float4*)&efs[r * 64 + sw] = w;
        }
        __syncthreads();
        float a0 = 0.f, a1 = 0.f, a2 = 0.f, a3 = 0.f;
        #pragma unroll
        for (int q = 0; q < 16; ++q) {
            float4 xv0 = *(const float4*)&xs[r0 * 64 + ((q ^ r0s) << 2)];
            float4 xv1 = *(const float4*)&xs[r1 * 64 + ((q ^ r1s) << 2)];
            float4 e0 = *(const float4*)&efs[eg * 64 + ((q ^ eg) << 2)];
            float4 e1 = *(const float4*)&efs[(eg + 16) * 64 + ((q ^ eg) << 2)];
            a0 = fmaf(xv0.x, e0.x, a0); a0 = fmaf(xv0.y, e0.y, a0);
            a0 = fmaf(xv0.z, e0.z, a0); a0 = fmaf(xv0.w, e0.w, a0);
            a1 = fmaf(xv0.x, e1.x, a1); a1 = fmaf(xv0.y, e1.y, a1);
            a1 = fmaf(xv0.z, e1.z, a1); a1 = fmaf(xv0.w, e1.w, a1);
            a2 = fmaf(xv1.x, e0.x, a2); a2 = fmaf(xv1.y, e0.y, a2);
            a2 = fmaf(xv1.z, e0.z, a2); a2 = fmaf(xv1.w, e0.w, a2);
            a3 = fmaf(xv1.x, e1.x, a3); a3 = fmaf(xv1.y, e1.y, a3);
            a3 = fmaf(xv1.z, e1.z, a3); a3 = fmaf(xv1.w, e1.w, a3);
        }
        __syncthreads();
        accd[0] += (double)a0; accd[1] += (double)a1;
        accd[2] += (double)a2; accd[3] += (double)a3;
    }

    #pragma unroll
    for (int ti = 0; ti < 2; ++ti) {
        int t = tb + 2 * tp + ti;
        double xn = fmax(xnorm[t], 1e-8);
        #pragma unroll
        for (int ej = 0; ej < 2; ++ej) {
            int e = eg + 16 * ej;
            double en = fmax(efn[e], 1e-8);
            double cosv = accd[ti * 2 + ej] / (xn * en);
            sc[(2 * tp + ti) * 32 + e] = 0.4 * (double)trust[e]
                + 0.2 * (cosv + 1.0)
                + 0.2 * fmax(0.0, 1.0 - (double)stale[e]);
        }
    }
    __syncthreads();

    // top-k (strict > scan, lowest-index tie-break == jax.lax.top_k set)
    if (tid < 32) {
        int kk = kp[0]; kk = kk < 1 ? 1 : (kk > KMAX ? KMAX : kk);
        unsigned mask = 0;
        int t = tb + tid;
        for (int p = 0; p < kk; ++p) {
            double bv = -1e300; int be = 0;
            #pragma unroll
            for (int e = 0; e < 32; ++e) {
                double v = sc[tid * 32 + e];
                if (!((mask >> e) & 1u) && v > bv) { bv = v; be = e; }
            }
            mask |= 1u << be;
            int pos = atomicAdd(&counts[be], 1);
            lists[(size_t)be * B + pos] = t;
        }
    }
}

// ---------------------------------------------------------------------------
// K4: grouped expert GEMM, bf16 MFMA, global_load_lds staging.
// grid = (ceil(B/128), C/128, E), 256 threads = 4 waves (2x2), BK=64.
// LDS tiles [128][64] bf16, pitch 128B, XOR swizzle seg^=(row&7):
// stage with inverse-swizzled per-lane GLOBAL source + linear LDS dest
// (global_load_lds writes base+lane*16), read frags with the same XOR ->
// conflict-free ds_read_b128.  Epilogue: out += (acc+bias)/k atomics.
// ---------------------------------------------------------------------------
__global__ __launch_bounds__(256) void k_moe2(
    const ushort* __restrict__ xbf, const ushort* __restrict__ wbf,
    const float* __restrict__ bias, const int* __restrict__ lists,
    const int* __restrict__ counts, const int* __restrict__ kp,
    int B, int C, int D, float* __restrict__ out)
{
    int e = blockIdx.z;
    int cnt = counts[e];
    int row0 = blockIdx.x * 128;
    if (row0 >= cnt) return;            // uniform: safe before barriers
    int col0 = blockIdx.y * 128;
    int nt = min(128, cnt - row0);

    __shared__ ushort xs[128 * 64];     // 16 KB
    __shared__ ushort wsh[128 * 64];    // 16 KB
    __shared__ int toks[128];

    int tid = threadIdx.x;
    if (tid < 128) toks[tid] = (tid < nt) ? lists[(size_t)e * B + row0 + tid] : 0;
    __syncthreads();

    int lane = tid & 63, wid = tid >> 6;
    int wr = wid >> 1, wc = wid & 1;    // wave tile: rows wr*64, cols wc*64
    int l15 = lane & 15, l16 = lane >> 4;

    f32x4 acc[4][4];
    #pragma unroll
    for (int m = 0; m < 4; ++m)
        #pragma unroll
        for (int n = 0; n < 4; ++n) acc[m][n] = (f32x4){0.f, 0.f, 0.f, 0.f};

    int nch = D / 64;
    for (int ch = 0; ch < nch; ++ch) {
        int k0 = ch * 64;
        // stage: 1024 ids each (row = id>>3, seg = id&7), 4 issues/wave/tile
        #pragma unroll
        for (int t = 0; t < 4; ++t) {
            int id = t * 256 + wid * 64 + lane;
            int r = id >> 3, seg = id & 7;
            int ssw = (seg ^ (r & 7)) << 3;
            const ushort* gx = &xbf[(size_t)toks[r] * D + k0 + ssw];
            gload_lds16(gx, (char*)xs + (t * 256 + wid * 64) * 16);
            const ushort* gw = &wbf[((size_t)e * C + col0 + r) * D + k0 + ssw];
            gload_lds16(gw, (char*)wsh + (t * 256 + wid * 64) * 16);
        }
        __syncthreads();
        #pragma unroll
        for (int ks = 0; ks < 2; ++ks) {
            s16x8 a[4], bfr[4];
            int sbase = ks * 4 + l16;
            #pragma unroll
            for (int m = 0; m < 4; ++m) {
                int r = wr * 64 + m * 16 + l15;
                a[m] = *(const s16x8*)&xs[r * 64 + ((sbase ^ (l15 & 7)) << 3)];
            }
            #pragma unroll
            for (int n = 0; n < 4; ++n) {
                int r = wc * 64 + n * 16 + l15;
                bfr[n] = *(const s16x8*)&wsh[r * 64 + ((sbase ^ (l15 & 7)) << 3)];
            }
            #pragma unroll
            for (int m = 0; m < 4; ++m)
                #pragma unroll
                for (int n = 0; n < 4; ++n)
                    acc[m][n] = __builtin_amdgcn_mfma_f32_16x16x32_bf16(
                        a[m], bfr[n], acc[m][n], 0, 0, 0);
        }
        __syncthreads();
    }

    int kk = kp[0]; kk = kk < 1 ? 1 : (kk > KMAX ? KMAX : kk);
    float invk = 1.0f / (float)kk;
    // C/D layout (m89): col = lane&15, row = (lane>>4)*4 + reg
    #pragma unroll
    for (int m = 0; m < 4; ++m) {
        int rbase = wr * 64 + m * 16 + l16 * 4;
        #pragma unroll
        for (int n = 0; n < 4; ++n) {
            int col = col0 + wc * 64 + n * 16 + l15;
            float bv = bias[(size_t)e * C + col];
            #pragma unroll
            for (int r = 0; r < 4; ++r) {
                int rl = rbase + r;
                if (rl < nt)
                    atomicAdd(&out[(size_t)toks[rl] * C + col],
                              invk * (acc[m][n][r] + bv));
            }
        }
    }
}

// ===========================================================================
// Legacy fallback (round-2 kernels) — used only if ws_size is too small for
// the bf16 mirrors.
// ===========================================================================
__global__ __launch_bounds__(256) void k_scores_legacy(
    const float* __restrict__ x, const float* __restrict__ ef,
    const float* __restrict__ trust, const float* __restrict__ stale,
    const double* __restrict__ efn, const int* __restrict__ kp,
    int D, int B, int* __restrict__ counts, int* __restrict__ lists)
{
    __shared__ float xs[32][72];
    __shared__ float efs[32][72];
    __shared__ double sc[32][32];

    int tid = threadIdx.x;
    int tl = tid >> 3, eg = tid & 7;
    int tb = blockIdx.x * 32;

    double acc[4] = {0, 0, 0, 0};
    double axx = 0.0;
    int nch = D / 64;

    for (int ch = 0; ch < nch; ++ch) {
        #pragma unroll
        for (int t = 0; t < 2; ++t) {
            int id = t * 256 + tid;
            int r = id >> 4, q = id & 15;
            float4 v = *(const float4*)&x[(size_t)(tb + r) * D + ch * 64 + q * 4];
            *(float4*)&xs[r][q * 4] = v;
            float4 w = *(const float4*)&ef[(size_t)r * D + ch * 64 + q * 4];
            *(float4*)&efs[r][q * 4] = w;
        }
        __syncthreads();
        #pragma unroll 4
        for (int q = 0; q < 16; ++q) {
            float4 xv = *(const float4*)&xs[tl][q * 4];
            double x0 = xv.x, x1 = xv.y, x2 = xv.z, x3 = xv.w;
            axx = fma(x0, x0, fma(x1, x1, fma(x2, x2, fma(x3, x3, axx))));
            #pragma unroll
            for (int j = 0; j < 4; ++j) {
                float4 ev = *(const float4*)&efs[eg + 8 * j][q * 4];
                acc[j] = fma(x0, (double)ev.x, acc[j]);
                acc[j] = fma(x1, (double)ev.y, acc[j]);
                acc[j] = fma(x2, (double)ev.z, acc[j]);
                acc[j] = fma(x3, (double)ev.w, acc[j]);
            }
        }
        __syncthreads();
    }

    double xn = fmax(sqrt(axx), 1e-8);
    #pragma unroll
    for (int j = 0; j < 4; ++j) {
        int e = eg + 8 * j;
        double en = fmax(efn[e], 1e-8);
        double cosv = acc[j] / (xn * en);
        sc[tl][e] = 0.4 * (double)trust[e] + 0.2 * (cosv + 1.0)
                  + 0.2 * fmax(0.0, 1.0 - (double)stale[e]);
    }
    __syncthreads();

    if (tid < 32) {
        int kk = kp[0]; kk = kk < 1 ? 1 : (kk > KMAX ? KMAX : kk);
        unsigned mask = 0;
        int t = tb + tid;
        for (int p = 0; p < kk; ++p) {
            double bv = -1e300; int be = 0;
            #pragma unroll
            for (int e = 0; e < 32; ++e) {
                double v = sc[tid][e];
                if (!((mask >> e) & 1u) && v > bv) { bv = v; be = e; }
            }
            mask |= 1u << be;
            int pos = atomicAdd(&counts[be], 1);
            lists[(size_t)be * B + pos] = t;
        }
    }
}

__global__ __launch_bounds__(512) void k_moe_f32(
    const float* __restrict__ x, const float* __restrict__ W,
    const float* __restrict__ bias, const int* __restrict__ lists,
    const int* __restrict__ counts, const int* __restrict__ kp,
    int B, int C, int D, float* __restrict__ out)
{
    int e = blockIdx.z;
    int cnt = counts[e];
    int row0 = blockIdx.x * 128;
    if (row0 >= cnt) return;
    int col0 = blockIdx.y * 256;
    int nt = min(128, cnt - row0);

    __shared__ ushort xs[128 * 72];
    __shared__ ushort wsh[256 * 72];
    __shared__ int toks[128];

    int tid = threadIdx.x;
    if (tid < 128) toks[tid] = (tid < nt) ? lists[(size_t)e * B + row0 + tid] : 0;
    __syncthreads();

    int lane = tid & 63, wid = tid >> 6;
    int wr = wid >> 2, wc = wid & 3;
    int l15 = lane & 15, l16 = lane >> 4;

    f32x4 acc[4][4];
    #pragma unroll
    for (int m = 0; m < 4; ++m)
        #pragma unroll
        for (int n = 0; n < 4; ++n) acc[m][n] = (f32x4){0.f, 0.f, 0.f, 0.f};

    int nch = D / 64;
    for (int ch = 0; ch < nch; ++ch) {
        int k0 = ch * 64;
        #pragma unroll
        for (int t = 0; t < 4; ++t) {
            int id = t * 512 + tid;
            int r = id >> 4, q = id & 15;
            float4 v = (r < nt)
                ? *(const float4*)&x[(size_t)toks[r] * D + k0 + q * 4]
                : make_float4(0.f, 0.f, 0.f, 0.f);
            ushort4 u;
            u.x = f2bf(v.x); u.y = f2bf(v.y); u.z = f2bf(v.z); u.w = f2bf(v.w);
            *(ushort4*)&xs[r * 72 + q * 4] = u;
        }
        #pragma unroll
        for (int t = 0; t < 8; ++t) {
            int id = t * 512 + tid;
            int r = id >> 4, q = id & 15;
            float4 v = *(const float4*)&W[((size_t)e * C + col0 + r) * D + k0 + q * 4];
            ushort4 u;
            u.x = f2bf(v.x); u.y = f2bf(v.y); u.z = f2bf(v.z); u.w = f2bf(v.w);
            *(ushort4*)&wsh[r * 72 + q * 4] = u;
        }
        __syncthreads();
        #pragma unroll
        for (int ks = 0; ks < 2; ++ks) {
            s16x8 a[4], bfr[4];
            #pragma unroll
            for (int m = 0; m < 4; ++m)
                a[m] = *(const s16x8*)&xs[(wr * 64 + m * 16 + l15) * 72 + ks * 32 + l16 * 8];
            #pragma unroll
            for (int n = 0; n < 4; ++n)
                bfr[n] = *(const s16x8*)&wsh[(wc * 64 + n * 16 + l15) * 72 + ks * 32 + l16 * 8];
            #pragma unroll
            for (int m = 0; m < 4; ++m)
                #pragma unroll
                for (int n = 0; n < 4; ++n)
                    acc[m][n] = __builtin_amdgcn_mfma_f32_16x16x32_bf16(
                        a[m], bfr[n], acc[m][n], 0, 0, 0);
        }
        __syncthreads();
    }

    int kk = kp[0]; kk = kk < 1 ? 1 : (kk > KMAX ? KMAX : kk);
    float invk = 1.0f / (float)kk;
    #pragma unroll
    for (int m = 0; m < 4; ++m) {
        int rbase = wr * 64 + m * 16 + l16 * 4;
        #pragma unroll
        for (int n = 0; n < 4; ++n) {
            int col = col0 + wc * 64 + n * 16 + l15;
            float bv = bias[(size_t)e * C + col];
            #pragma unroll
            for (int r = 0; r < 4; ++r) {
                int rl = rbase + r;
                if (rl < nt)
                    atomicAdd(&out[(size_t)toks[rl] * C + col],
                              invk * (acc[m][n][r] + bv));
            }
        }
    }
}

// ---------------------------------------------------------------------------
extern "C" void kernel_launch(void* const* d_in, const int* in_sizes, int n_in,
                              void* d_out, int out_size, void* d_ws, size_t ws_size,
                              hipStream_t stream) {
    const float* x     = (const float*)d_in[0];
    const float* ef    = (const float*)d_in[1];
    const float* trust = (const float*)d_in[2];
    const float* stale = (const float*)d_in[3];
    const float* W     = (const float*)d_in[4];
    const float* b     = (const float*)d_in[5];
    const int*   kp    = (const int*)d_in[6];

    int E = in_sizes[2];            // 32
    int D = in_sizes[1] / E;        // 1024
    int B = in_sizes[0] / D;        // 8192
    int C = in_sizes[5] / E;        // 256
    float* out = (float*)d_out;

    // workspace layout
    char* ws = (char*)d_ws;
    double* efn   = (double*)ws;                       // 256 B
    int*    counts= (int*)(ws + 256);                  // 256 B
    double* xnorm = (double*)(ws + 512);               // B*8
    size_t off_lists = 512 + (size_t)B * 8;
    int*    lists = (int*)(ws + off_lists);            // E*B*4
    size_t off_xbf = off_lists + (size_t)E * B * 4;
    off_xbf = (off_xbf + 255) & ~(size_t)255;
    ushort* xbf = (ushort*)(ws + off_xbf);             // B*D*2
    size_t off_wbf = off_xbf + (size_t)B * D * 2;
    ushort* wbf = (ushort*)(ws + off_wbf);             // E*C*D*2
    size_t need = off_wbf + (size_t)E * C * D * 2;

    hipMemsetAsync(counts, 0, 256, stream);
    hipMemsetAsync(d_out, 0, (size_t)out_size * sizeof(float), stream);

    k_efnorm<<<E, 64, 0, stream>>>(ef, D, efn);

    if (ws_size >= need) {
        k_prep_x<<<B / 4, 256, 0, stream>>>(x, D, xbf, xnorm);
        int nw4 = (E * C * D) / 1024;   // float4s per block = 256
        k_prep_w<<<nw4, 256, 0, stream>>>(W, wbf);
        k_scores2<<<B / 32, 256, 0, stream>>>(x, ef, trust, stale, efn, xnorm,
                                              kp, D, B, counts, lists);
        dim3 grid((B + 127) / 128, C / 128, E);
        k_moe2<<<grid, 256, 0, stream>>>(xbf, wbf, b, lists, counts, kp,
                                         B, C, D, out);
    } else {
        k_scores_legacy<<<B / 32, 256, 0, stream>>>(x, ef, trust, stale, efn,
                                                    kp, D, B, counts, lists);
        dim3 grid((B + 127) / 128, C / 256, E);
        k_moe_f32<<<grid, 512, 0, stream>>>(x, W, b, lists, counts, kp,
                                            B, C, D, out);
    }
}

// Round 4
// 126.892 us; speedup vs baseline: 6.1046x; 3.3802x over previous
//
#include <hip/hip_runtime.h>
#include <math.h>

#define KMAX 8
#define CSTRIDE 64   // ints between expert counters = 256 B -> distinct cache lines

typedef short s16x8 __attribute__((ext_vector_type(8)));
typedef float f32x4 __attribute__((ext_vector_type(4)));

__device__ inline ushort f2bf(float f) {
    union { float f; unsigned u; } v; v.f = f;
    unsigned r = v.u + 0x7fffu + ((v.u >> 16) & 1u);   // RNE
    return (ushort)(r >> 16);
}

__device__ inline void gload_lds16(const void* g, void* l) {
    __builtin_amdgcn_global_load_lds(
        (const __attribute__((address_space(1))) unsigned int*)g,
        (__attribute__((address_space(3))) unsigned int*)l, 16, 0, 0);
}

// ---------------------------------------------------------------------------
// K0: per-expert feature norms in double.  grid = E blocks of 64 threads.
// ---------------------------------------------------------------------------
__global__ void k_efnorm(const float* __restrict__ ef, int D,
                         double* __restrict__ efn) {
    int e = blockIdx.x;
    int lane = threadIdx.x;  // 64
    double s = 0.0;
    for (int i = lane; i < D; i += 64) {
        double v = (double)ef[(size_t)e * D + i];
        s = fma(v, v, s);
    }
    #pragma unroll
    for (int off = 32; off > 0; off >>= 1) s += __shfl_xor(s, off);
    if (lane == 0) efn[e] = sqrt(s);
}

// ---------------------------------------------------------------------------
// K1: x -> bf16 copy + per-token L2 norm (f64).  4 tokens/block, wave/token.
// ---------------------------------------------------------------------------
__global__ __launch_bounds__(256) void k_prep_x(
    const float* __restrict__ x, int D, ushort* __restrict__ xbf,
    double* __restrict__ xnorm) {
    int t = blockIdx.x * 4 + (threadIdx.x >> 6);
    int lane = threadIdx.x & 63;
    double s = 0.0;
    int nq = D / 256;
    for (int q = 0; q < nq; ++q) {
        float4 v = *(const float4*)&x[(size_t)t * D + q * 256 + lane * 4];
        ushort4 u;
        u.x = f2bf(v.x); u.y = f2bf(v.y); u.z = f2bf(v.z); u.w = f2bf(v.w);
        *(ushort4*)&xbf[(size_t)t * D + q * 256 + lane * 4] = u;
        double a = v.x, b = v.y, c = v.z, d = v.w;
        s = fma(a, a, fma(b, b, fma(c, c, fma(d, d, s))));
    }
    #pragma unroll
    for (int off = 32; off > 0; off >>= 1) s += __shfl_xor(s, off);
    if (lane == 0) xnorm[t] = sqrt(s);
}

// ---------------------------------------------------------------------------
// K2: W -> bf16.  grid covers n/4 elements exactly (n % 1024 == 0).
// ---------------------------------------------------------------------------
__global__ __launch_bounds__(256) void k_prep_w(
    const float* __restrict__ W, ushort* __restrict__ wbf) {
    size_t id = (size_t)blockIdx.x * 256 + threadIdx.x;
    float4 v = *(const float4*)&W[id * 4];
    ushort4 u;
    u.x = f2bf(v.x); u.y = f2bf(v.y); u.z = f2bf(v.z); u.w = f2bf(v.w);
    *(ushort4*)&wbf[id * 4] = u;
}

// ---------------------------------------------------------------------------
// K3: scores + top-k + scatter.  32 tokens/block, 256 threads, B/32 blocks.
// Dots: f32 FMA per 64-chunk, f64 accumulation across chunks (perturbation
// ~1e-9, proven tolerated by rounds 1-3).
// Scatter is HIERARCHICAL: LDS per-block expert counters, then ONE global
// atomicAdd per (block, expert) onto 256B-spaced counters (32 distinct cache
// lines).  This replaces 32768 same-line device atomics (the 330 us stall of
// rounds 1-3) with <=8192 spread over 32 lines.
// ---------------------------------------------------------------------------
__global__ __launch_bounds__(256) void k_scores2(
    const float* __restrict__ x, const float* __restrict__ ef,
    const float* __restrict__ trust, const float* __restrict__ stale,
    const double* __restrict__ efn, const double* __restrict__ xnorm,
    const int* __restrict__ kp, int D, int B,
    int* __restrict__ counts, int* __restrict__ lists)
{
    __shared__ float xs[32 * 64];
    __shared__ float efs[32 * 64];
    __shared__ double sc[32 * 33];          // stride 33: conflict-free scan
    __shared__ int bcnt[32];
    __shared__ int bbase[32];
    __shared__ unsigned char selb[32 * KMAX];
    __shared__ unsigned char lposb[32 * KMAX];

    int tid = threadIdx.x;
    int tp = tid >> 4, eg = tid & 15;
    int tb = blockIdx.x * 32;
    int r0 = 2 * tp, r1 = 2 * tp + 1;
    int r0s = r0 & 15, r1s = r1 & 15;

    if (tid < 32) bcnt[tid] = 0;

    double accd[4] = {0, 0, 0, 0};
    int nch = D / 64;

    for (int ch = 0; ch < nch; ++ch) {
        #pragma unroll
        for (int t = 0; t < 2; ++t) {
            int id = t * 256 + tid;
            int r = id >> 4, q = id & 15;
            int sw = (q ^ (r & 15)) << 2;
            float4 v = *(const float4*)&x[(size_t)(tb + r) * D + ch * 64 + q * 4];
            *(float4*)&xs[r * 64 + sw] = v;
            float4 w = *(const float4*)&ef[(size_t)r * D + ch * 64 + q * 4];
            *(float4*)&efs[r * 64 + sw] = w;
        }
        __syncthreads();
        float a0 = 0.f, a1 = 0.f, a2 = 0.f, a3 = 0.f;
        #pragma unroll
        for (int q = 0; q < 16; ++q) {
            float4 xv0 = *(const float4*)&xs[r0 * 64 + ((q ^ r0s) << 2)];
            float4 xv1 = *(const float4*)&xs[r1 * 64 + ((q ^ r1s) << 2)];
            float4 e0 = *(const float4*)&efs[eg * 64 + ((q ^ eg) << 2)];
            float4 e1 = *(const float4*)&efs[(eg + 16) * 64 + ((q ^ eg) << 2)];
            a0 = fmaf(xv0.x, e0.x, a0); a0 = fmaf(xv0.y, e0.y, a0);
            a0 = fmaf(xv0.z, e0.z, a0); a0 = fmaf(xv0.w, e0.w, a0);
            a1 = fmaf(xv0.x, e1.x, a1); a1 = fmaf(xv0.y, e1.y, a1);
            a1 = fmaf(xv0.z, e1.z, a1); a1 = fmaf(xv0.w, e1.w, a1);
            a2 = fmaf(xv1.x, e0.x, a2); a2 = fmaf(xv1.y, e0.y, a2);
            a2 = fmaf(xv1.z, e0.z, a2); a2 = fmaf(xv1.w, e0.w, a2);
            a3 = fmaf(xv1.x, e1.x, a3); a3 = fmaf(xv1.y, e1.y, a3);
            a3 = fmaf(xv1.z, e1.z, a3); a3 = fmaf(xv1.w, e1.w, a3);
        }
        __syncthreads();
        accd[0] += (double)a0; accd[1] += (double)a1;
        accd[2] += (double)a2; accd[3] += (double)a3;
    }

    #pragma unroll
    for (int ti = 0; ti < 2; ++ti) {
        int t = tb + 2 * tp + ti;
        double xn = fmax(xnorm[t], 1e-8);
        #pragma unroll
        for (int ej = 0; ej < 2; ++ej) {
            int e = eg + 16 * ej;
            double en = fmax(efn[e], 1e-8);
            double cosv = accd[ti * 2 + ej] / (xn * en);
            sc[(2 * tp + ti) * 33 + e] = 0.4 * (double)trust[e]
                + 0.2 * (cosv + 1.0)
                + 0.2 * fmax(0.0, 1.0 - (double)stale[e]);
        }
    }
    __syncthreads();

    int kk = kp[0]; kk = kk < 1 ? 1 : (kk > KMAX ? KMAX : kk);

    // per-token top-k (strict > scan, lowest-index tie-break == jax.lax.top_k
    // selected set); record selection + LDS-local position
    if (tid < 32) {
        unsigned mask = 0;
        for (int p = 0; p < kk; ++p) {
            double bv = -1e300; int be = 0;
            #pragma unroll
            for (int e = 0; e < 32; ++e) {
                double v = sc[tid * 33 + e];
                if (!((mask >> e) & 1u) && v > bv) { bv = v; be = e; }
            }
            mask |= 1u << be;
            selb[tid * KMAX + p] = (unsigned char)be;
            lposb[tid * KMAX + p] = (unsigned char)atomicAdd(&bcnt[be], 1);
        }
    }
    __syncthreads();
    if (tid < 32) {
        int c = bcnt[tid];
        bbase[tid] = c ? atomicAdd(&counts[tid * CSTRIDE], c) : 0;
    }
    __syncthreads();
    if (tid < 32) {
        int t = tb + tid;
        for (int p = 0; p < kk; ++p) {
            int e = selb[tid * KMAX + p];
            lists[(size_t)e * B + bbase[e] + lposb[tid * KMAX + p]] = t;
        }
    }
}

// ---------------------------------------------------------------------------
// K4: grouped expert GEMM, bf16 MFMA, global_load_lds staging.
// grid = (ceil(B/128), C/128, E), 256 threads = 4 waves (2x2), BK=64.
// LDS tiles [128][64] bf16, XOR swizzle seg^=(row&7) applied on the per-lane
// GLOBAL source (linear LDS dest) and on the ds_read address (m201 pattern).
// ---------------------------------------------------------------------------
__global__ __launch_bounds__(256) void k_moe2(
    const ushort* __restrict__ xbf, const ushort* __restrict__ wbf,
    const float* __restrict__ bias, const int* __restrict__ lists,
    const int* __restrict__ counts, const int* __restrict__ kp,
    int B, int C, int D, float* __restrict__ out)
{
    int e = blockIdx.z;
    int cnt = counts[e * CSTRIDE];
    int row0 = blockIdx.x * 128;
    if (row0 >= cnt) return;            // uniform: safe before barriers
    int col0 = blockIdx.y * 128;
    int nt = min(128, cnt - row0);

    __shared__ ushort xs[128 * 64];     // 16 KB
    __shared__ ushort wsh[128 * 64];    // 16 KB
    __shared__ int toks[128];

    int tid = threadIdx.x;
    if (tid < 128) toks[tid] = (tid < nt) ? lists[(size_t)e * B + row0 + tid] : 0;
    __syncthreads();

    int lane = tid & 63, wid = tid >> 6;
    int wr = wid >> 1, wc = wid & 1;    // wave tile: rows wr*64, cols wc*64
    int l15 = lane & 15, l16 = lane >> 4;

    f32x4 acc[4][4];
    #pragma unroll
    for (int m = 0; m < 4; ++m)
        #pragma unroll
        for (int n = 0; n < 4; ++n) acc[m][n] = (f32x4){0.f, 0.f, 0.f, 0.f};

    int nch = D / 64;
    for (int ch = 0; ch < nch; ++ch) {
        int k0 = ch * 64;
        #pragma unroll
        for (int t = 0; t < 4; ++t) {
            int id = t * 256 + wid * 64 + lane;
            int r = id >> 3, seg = id & 7;
            int ssw = (seg ^ (r & 7)) << 3;
            const ushort* gx = &xbf[(size_t)toks[r] * D + k0 + ssw];
            gload_lds16(gx, (char*)xs + (t * 256 + wid * 64) * 16);
            const ushort* gw = &wbf[((size_t)e * C + col0 + r) * D + k0 + ssw];
            gload_lds16(gw, (char*)wsh + (t * 256 + wid * 64) * 16);
        }
        __syncthreads();
        #pragma unroll
        for (int ks = 0; ks < 2; ++ks) {
            s16x8 a[4], bfr[4];
            int sbase = ks * 4 + l16;
            #pragma unroll
            for (int m = 0; m < 4; ++m) {
                int r = wr * 64 + m * 16 + l15;
                a[m] = *(const s16x8*)&xs[r * 64 + ((sbase ^ (l15 & 7)) << 3)];
            }
            #pragma unroll
            for (int n = 0; n < 4; ++n) {
                int r = wc * 64 + n * 16 + l15;
                bfr[n] = *(const s16x8*)&wsh[r * 64 + ((sbase ^ (l15 & 7)) << 3)];
            }
            #pragma unroll
            for (int m = 0; m < 4; ++m)
                #pragma unroll
                for (int n = 0; n < 4; ++n)
                    acc[m][n] = __builtin_amdgcn_mfma_f32_16x16x32_bf16(
                        a[m], bfr[n], acc[m][n], 0, 0, 0);
        }
        __syncthreads();
    }

    int kk = kp[0]; kk = kk < 1 ? 1 : (kk > KMAX ? KMAX : kk);
    float invk = 1.0f / (float)kk;
    // C/D layout (m89): col = lane&15, row = (lane>>4)*4 + reg
    #pragma unroll
    for (int m = 0; m < 4; ++m) {
        int rbase = wr * 64 + m * 16 + l16 * 4;
        #pragma unroll
        for (int n = 0; n < 4; ++n) {
            int col = col0 + wc * 64 + n * 16 + l15;
            float bv = bias[(size_t)e * C + col];
            #pragma unroll
            for (int r = 0; r < 4; ++r) {
                int rl = rbase + r;
                if (rl < nt)
                    atomicAdd(&out[(size_t)toks[rl] * C + col],
                              invk * (acc[m][n][r] + bv));
            }
        }
    }
}

// ===========================================================================
// Legacy fallback — only if ws_size is too small for the bf16 mirrors.
// ===========================================================================
__global__ __launch_bounds__(256) void k_scores_legacy(
    const float* __restrict__ x, const float* __restrict__ ef,
    const float* __restrict__ trust, const float* __restrict__ stale,
    const double* __restrict__ efn, const int* __restrict__ kp,
    int D, int B, int* __restrict__ counts, int* __restrict__ lists)
{
    __shared__ float xs[32][72];
    __shared__ float efs[32][72];
    __shared__ double sc[32][33];

    int tid = threadIdx.x;
    int tl = tid >> 3, eg = tid & 7;
    int tb = blockIdx.x * 32;

    double acc[4] = {0, 0, 0, 0};
    double axx = 0.0;
    int nch = D / 64;

    for (int ch = 0; ch < nch; ++ch) {
        #pragma unroll
        for (int t = 0; t < 2; ++t) {
            int id = t * 256 + tid;
            int r = id >> 4, q = id & 15;
            float4 v = *(const float4*)&x[(size_t)(tb + r) * D + ch * 64 + q * 4];
            *(float4*)&xs[r][q * 4] = v;
            float4 w = *(const float4*)&ef[(size_t)r * D + ch * 64 + q * 4];
            *(float4*)&efs[r][q * 4] = w;
        }
        __syncthreads();
        #pragma unroll 4
        for (int q = 0; q < 16; ++q) {
            float4 xv = *(const float4*)&xs[tl][q * 4];
            double x0 = xv.x, x1 = xv.y, x2 = xv.z, x3 = xv.w;
            axx = fma(x0, x0, fma(x1, x1, fma(x2, x2, fma(x3, x3, axx))));
            #pragma unroll
            for (int j = 0; j < 4; ++j) {
                float4 ev = *(const float4*)&efs[eg + 8 * j][q * 4];
                acc[j] = fma(x0, (double)ev.x, acc[j]);
                acc[j] = fma(x1, (double)ev.y, acc[j]);
                acc[j] = fma(x2, (double)ev.z, acc[j]);
                acc[j] = fma(x3, (double)ev.w, acc[j]);
            }
        }
        __syncthreads();
    }

    double xn = fmax(sqrt(axx), 1e-8);
    #pragma unroll
    for (int j = 0; j < 4; ++j) {
        int e = eg + 8 * j;
        double en = fmax(efn[e], 1e-8);
        double cosv = acc[j] / (xn * en);
        sc[tl][e] = 0.4 * (double)trust[e] + 0.2 * (cosv + 1.0)
                  + 0.2 * fmax(0.0, 1.0 - (double)stale[e]);
    }
    __syncthreads();

    if (tid < 32) {
        int kk = kp[0]; kk = kk < 1 ? 1 : (kk > KMAX ? KMAX : kk);
        unsigned mask = 0;
        int t = tb + tid;
        for (int p = 0; p < kk; ++p) {
            double bv = -1e300; int be = 0;
            #pragma unroll
            for (int e = 0; e < 32; ++e) {
                double v = sc[tid][e];
                if (!((mask >> e) & 1u) && v > bv) { bv = v; be = e; }
            }
            mask |= 1u << be;
            int pos = atomicAdd(&counts[be * CSTRIDE], 1);
            lists[(size_t)be * B + pos] = t;
        }
    }
}

__global__ __launch_bounds__(512) void k_moe_f32(
    const float* __restrict__ x, const float* __restrict__ W,
    const float* __restrict__ bias, const int* __restrict__ lists,
    const int* __restrict__ counts, const int* __restrict__ kp,
    int B, int C, int D, float* __restrict__ out)
{
    int e = blockIdx.z;
    int cnt = counts[e * CSTRIDE];
    int row0 = blockIdx.x * 128;
    if (row0 >= cnt) return;
    int col0 = blockIdx.y * 256;
    int nt = min(128, cnt - row0);

    __shared__ ushort xs[128 * 72];
    __shared__ ushort wsh[256 * 72];
    __shared__ int toks[128];

    int tid = threadIdx.x;
    if (tid < 128) toks[tid] = (tid < nt) ? lists[(size_t)e * B + row0 + tid] : 0;
    __syncthreads();

    int lane = tid & 63, wid = tid >> 6;
    int wr = wid >> 2, wc = wid & 3;
    int l15 = lane & 15, l16 = lane >> 4;

    f32x4 acc[4][4];
    #pragma unroll
    for (int m = 0; m < 4; ++m)
        #pragma unroll
        for (int n = 0; n < 4; ++n) acc[m][n] = (f32x4){0.f, 0.f, 0.f, 0.f};

    int nch = D / 64;
    for (int ch = 0; ch < nch; ++ch) {
        int k0 = ch * 64;
        #pragma unroll
        for (int t = 0; t < 4; ++t) {
            int id = t * 512 + tid;
            int r = id >> 4, q = id & 15;
            float4 v = (r < nt)
                ? *(const float4*)&x[(size_t)toks[r] * D + k0 + q * 4]
                : make_float4(0.f, 0.f, 0.f, 0.f);
            ushort4 u;
            u.x = f2bf(v.x); u.y = f2bf(v.y); u.z = f2bf(v.z); u.w = f2bf(v.w);
            *(ushort4*)&xs[r * 72 + q * 4] = u;
        }
        #pragma unroll
        for (int t = 0; t < 8; ++t) {
            int id = t * 512 + tid;
            int r = id >> 4, q = id & 15;
            float4 v = *(const float4*)&W[((size_t)e * C + col0 + r) * D + k0 + q * 4];
            ushort4 u;
            u.x = f2bf(v.x); u.y = f2bf(v.y); u.z = f2bf(v.z); u.w = f2bf(v.w);
            *(ushort4*)&wsh[r * 72 + q * 4] = u;
        }
        __syncthreads();
        #pragma unroll
        for (int ks = 0; ks < 2; ++ks) {
            s16x8 a[4], bfr[4];
            #pragma unroll
            for (int m = 0; m < 4; ++m)
                a[m] = *(const s16x8*)&xs[(wr * 64 + m * 16 + l15) * 72 + ks * 32 + l16 * 8];
            #pragma unroll
            for (int n = 0; n < 4; ++n)
                bfr[n] = *(const s16x8*)&wsh[(wc * 64 + n * 16 + l15) * 72 + ks * 32 + l16 * 8];
            #pragma unroll
            for (int m = 0; m < 4; ++m)
                #pragma unroll
                for (int n = 0; n < 4; ++n)
                    acc[m][n] = __builtin_amdgcn_mfma_f32_16x16x32_bf16(
                        a[m], bfr[n], acc[m][n], 0, 0, 0);
        }
        __syncthreads();
    }

    int kk = kp[0]; kk = kk < 1 ? 1 : (kk > KMAX ? KMAX : kk);
    float invk = 1.0f / (float)kk;
    #pragma unroll
    for (int m = 0; m < 4; ++m) {
        int rbase = wr * 64 + m * 16 + l16 * 4;
        #pragma unroll
        for (int n = 0; n < 4; ++n) {
            int col = col0 + wc * 64 + n * 16 + l15;
            float bv = bias[(size_t)e * C + col];
            #pragma unroll
            for (int r = 0; r < 4; ++r) {
                int rl = rbase + r;
                if (rl < nt)
                    atomicAdd(&out[(size_t)toks[rl] * C + col],
                              invk * (acc[m][n][r] + bv));
            }
        }
    }
}

// ---------------------------------------------------------------------------
extern "C" void kernel_launch(void* const* d_in, const int* in_sizes, int n_in,
                              void* d_out, int out_size, void* d_ws, size_t ws_size,
                              hipStream_t stream) {
    const float* x     = (const float*)d_in[0];
    const float* ef    = (const float*)d_in[1];
    const float* trust = (const float*)d_in[2];
    const float* stale = (const float*)d_in[3];
    const float* W     = (const float*)d_in[4];
    const float* b     = (const float*)d_in[5];
    const int*   kp    = (const int*)d_in[6];

    int E = in_sizes[2];            // 32
    int D = in_sizes[1] / E;        // 1024
    int B = in_sizes[0] / D;        // 8192
    int C = in_sizes[5] / E;        // 256
    float* out = (float*)d_out;

    // workspace layout
    char* ws = (char*)d_ws;
    double* efn   = (double*)ws;                       // 256 B
    int*    counts= (int*)(ws + 256);                  // 32*CSTRIDE*4 = 8 KB
    size_t off_xn = 256 + 32 * CSTRIDE * 4;
    double* xnorm = (double*)(ws + off_xn);            // B*8
    size_t off_lists = off_xn + (size_t)B * 8;
    int*    lists = (int*)(ws + off_lists);            // E*B*4
    size_t off_xbf = off_lists + (size_t)E * B * 4;
    off_xbf = (off_xbf + 255) & ~(size_t)255;
    ushort* xbf = (ushort*)(ws + off_xbf);             // B*D*2
    size_t off_wbf = off_xbf + (size_t)B * D * 2;
    ushort* wbf = (ushort*)(ws + off_wbf);             // E*C*D*2
    size_t need = off_wbf + (size_t)E * C * D * 2;

    hipMemsetAsync(counts, 0, 32 * CSTRIDE * 4, stream);
    hipMemsetAsync(d_out, 0, (size_t)out_size * sizeof(float), stream);

    k_efnorm<<<E, 64, 0, stream>>>(ef, D, efn);

    if (ws_size >= need) {
        k_prep_x<<<B / 4, 256, 0, stream>>>(x, D, xbf, xnorm);
        int nw4 = (E * C * D) / 1024;   // float4s per block = 256
        k_prep_w<<<nw4, 256, 0, stream>>>(W, wbf);
        k_scores2<<<B / 32, 256, 0, stream>>>(x, ef, trust, stale, efn, xnorm,
                                              kp, D, B, counts, lists);
        dim3 grid((B + 127) / 128, C / 128, E);
        k_moe2<<<grid, 256, 0, stream>>>(xbf, wbf, b, lists, counts, kp,
                                         B, C, D, out);
    } else {
        k_scores_legacy<<<B / 32, 256, 0, stream>>>(x, ef, trust, stale, efn,
                                                    kp, D, B, counts, lists);
        dim3 grid((B + 127) / 128, C / 256, E);
        k_moe_f32<<<grid, 512, 0, stream>>>(x, W, b, lists, counts, kp,
                                            B, C, D, out);
    }
}